// Round 6
// baseline (203.451 us; speedup 1.0000x reference)
//
#include <hip/hip_runtime.h>
#include <hip/hip_bf16.h>

#define B_SZ 8
#define T_SZ 1024
#define D_IN 512
#define D_H  64
#define N_H  8

typedef __hip_bfloat16 bf16;
using short8  = __attribute__((ext_vector_type(8))) short;
using short4v = __attribute__((ext_vector_type(4))) short;
using f32x4   = __attribute__((ext_vector_type(4))) float;

__device__ __forceinline__ unsigned short f2bf(float f) {
    union { __hip_bfloat16 b; unsigned short u; } c;
    c.b = __float2bfloat16(f);
    return c.u;
}

// ---------------------------------------------------------------------------
// prep: W[i][d][h] fp32 -> Wt[mat][n=h*64+d][k=i] bf16 (1.5 MB), plus
// padf[b][t] = -1000 if key_seq==-1 else 0.  grid (1024, 3) x 256.
// ---------------------------------------------------------------------------
__global__ __launch_bounds__(256) void prep_kernel(
    const float* __restrict__ Wk, const float* __restrict__ Wq,
    const float* __restrict__ Wv, const int* __restrict__ key_seq,
    unsigned short* __restrict__ Wt, float* __restrict__ padf)
{
    const int mat = blockIdx.y;
    const float* W = (mat == 0) ? Wk : (mat == 1) ? Wq : Wv;
    int idx = blockIdx.x * 256 + threadIdx.x;        // 0..262143
    float v = W[idx];
    int k = idx >> 9, c = idx & 511;                 // c = d*8 + h
    int h = c & 7, d = c >> 3;
    Wt[(((size_t)mat * 8 + h) * 64 + d) * 512 + k] = f2bf(v);
    if (mat == 2 && idx < B_SZ * T_SZ)
        padf[idx] = (key_seq[idx] == -1) ? -1000.f : 0.f;
}

// ---------------------------------------------------------------------------
// MFMA projection, 128x128 tiles (all 8 heads per mat in one N range).
// grid (8192/128, 3*4), block 256 = 4 waves in 2x2, wave tile 64x64.
// P[mat][b*8+h][t][d] bf16.
// ---------------------------------------------------------------------------
__global__ __launch_bounds__(256) void proj_kernel(
    const float* __restrict__ keys, const float* __restrict__ queries,
    const float* __restrict__ values,
    const unsigned short* __restrict__ Wt, unsigned short* __restrict__ KQVb)
{
    const int tid = threadIdx.x;
    const int m0  = blockIdx.x * 128;
    const int mat = blockIdx.y >> 2, ntile = blockIdx.y & 3;
    const int n0  = ntile * 128;

    const float* X = (mat == 0) ? keys : (mat == 1) ? queries : values;
    const unsigned short* WTm = Wt + (size_t)mat * 512 * 512;   // [n][k]
    unsigned short* P = KQVb + (size_t)mat * ((size_t)B_SZ * N_H * T_SZ * D_H);

    __shared__ __align__(16) unsigned short Ast[128 * 72];
    __shared__ __align__(16) unsigned short Bst[128 * 72];

    const int wid = tid >> 6, lane = tid & 63;
    const int quad = lane >> 4, l15 = lane & 15;
    const int wm = wid >> 1, wn = wid & 1;

    f32x4 acc[4][4];
    #pragma unroll
    for (int i = 0; i < 4; ++i)
        #pragma unroll
        for (int j = 0; j < 4; ++j) acc[i][j] = (f32x4){0.f, 0.f, 0.f, 0.f};

    const float4* X4 = (const float4*)X;

    for (int kc = 0; kc < 8; ++kc) {
        const int k0 = kc * 64;
        __syncthreads();
        // stage A: 128 rows x 64 k, fp32 -> bf16
        #pragma unroll
        for (int q = 0; q < 8; ++q) {
            int e = tid + q * 256;                   // 0..2047 float4s
            int r = e >> 4, c4 = e & 15;
            float4 v = X4[(size_t)(m0 + r) * (D_IN / 4) + (k0 >> 2) + c4];
            short4v s = {(short)f2bf(v.x), (short)f2bf(v.y),
                         (short)f2bf(v.z), (short)f2bf(v.w)};
            *(short4v*)&Ast[r * 72 + c4 * 4] = s;
        }
        // stage B: 128 n-rows x 64 k, b128 copies
        #pragma unroll
        for (int q = 0; q < 4; ++q) {
            int e = tid + q * 256;                   // 0..1023 short8s
            int r = e >> 3, ch = e & 7;
            *(short8*)&Bst[r * 72 + ch * 8] =
                *(const short8*)&WTm[(size_t)(n0 + r) * 512 + k0 + ch * 8];
        }
        __syncthreads();
        #pragma unroll
        for (int kc2 = 0; kc2 < 2; ++kc2) {
            short8 af[4], bfr[4];
            #pragma unroll
            for (int mt = 0; mt < 4; ++mt)
                af[mt] = *(const short8*)&Ast[(wm*64 + mt*16 + l15) * 72 + kc2*32 + quad*8];
            #pragma unroll
            for (int nt = 0; nt < 4; ++nt)
                bfr[nt] = *(const short8*)&Bst[(wn*64 + nt*16 + l15) * 72 + kc2*32 + quad*8];
            #pragma unroll
            for (int mt = 0; mt < 4; ++mt)
                #pragma unroll
                for (int nt = 0; nt < 4; ++nt)
                    acc[mt][nt] = __builtin_amdgcn_mfma_f32_16x16x32_bf16(
                        af[mt], bfr[nt], acc[mt][nt], 0, 0, 0);
        }
    }

    // epilogue: m = row (b,t), n = h*64+d
    #pragma unroll
    for (int mt = 0; mt < 4; ++mt)
        #pragma unroll
        for (int r = 0; r < 4; ++r) {
            int m = m0 + wm * 64 + mt * 16 + quad * 4 + r;
            int bb = m >> 10, t = m & 1023;
            #pragma unroll
            for (int nt = 0; nt < 4; ++nt) {
                int n = n0 + wn * 64 + nt * 16 + l15;
                int h = n >> 6, d = n & 63;
                P[(((size_t)(bb * 8 + h)) * 1024 + t) * 64 + d] =
                    f2bf(acc[mt][nt][r]);
            }
        }
}

// ---------------------------------------------------------------------------
// V transpose: Vb[bh][t][d] -> Vt[bh][d][t] bf16. grid (16, 64) x 256.
// ---------------------------------------------------------------------------
__global__ __launch_bounds__(256) void vt_kernel(
    const unsigned short* __restrict__ Vb, unsigned short* __restrict__ Vt)
{
    const int tid = threadIdx.x;
    const int t0  = blockIdx.x * 64;
    const int bh  = blockIdx.y;
    __shared__ __align__(16) unsigned short Tst[64 * 72];
    #pragma unroll
    for (int q = 0; q < 2; ++q) {
        int e = tid + q * 256;
        int t = e >> 3, ch = e & 7;
        *(short8*)&Tst[t * 72 + ch * 8] =
            *(const short8*)&Vb[((size_t)bh * T_SZ + t0 + t) * 64 + ch * 8];
    }
    __syncthreads();
    #pragma unroll
    for (int q = 0; q < 2; ++q) {
        int e = tid + q * 256;
        int d = e & 63, ch8 = e >> 6;     // d varies across lanes: LDS 2-way free
        short8 v;
        #pragma unroll
        for (int c = 0; c < 8; ++c) v[c] = (short)Tst[(ch8 * 8 + c) * 72 + d];
        *(short8*)&Vt[((size_t)bh * 64 + d) * 1024 + t0 + ch8 * 8] = v;
    }
}

// ---------------------------------------------------------------------------
// Barrier-free MFMA flash attention. 64-thread blocks (1 wave), j-strip 16.
// All MFMA frags loaded directly from global (L1/L2); only P round-trips
// through wave-private LDS. grid 4096 1D:
//   jt16 = 63 - (x>>6)  (high bits -> stride-256 CU assignment is balanced)
//   bh   = ((x&7)<<3) | ((x>>3)&7)  (x%8 fixed per bh-group -> XCD locality)
// ---------------------------------------------------------------------------
__global__ __launch_bounds__(64) void attn_kernel(
    const unsigned short* __restrict__ Qb, const unsigned short* __restrict__ Kb,
    const unsigned short* __restrict__ Vt, const float* __restrict__ padf,
    float* __restrict__ out)
{
    const int x    = blockIdx.x;
    const int jt16 = 63 - (x >> 6);
    const int bh6  = x & 63;
    const int bh   = ((bh6 & 7) << 3) | (bh6 >> 3);
    const int j0   = jt16 * 16;
    const int b    = bh >> 3, h = bh & 7;
    const int lane = threadIdx.x, quad = lane >> 4, l15 = lane & 15;

    __shared__ __align__(16) unsigned short PstT[16 * 72];   // [j][i]

    const size_t bhT = (size_t)bh * T_SZ;

    const short8 qf0 = *(const short8*)&Qb[(bhT + j0 + l15) * 64 + quad * 8];
    const short8 qf1 = *(const short8*)&Qb[(bhT + j0 + l15) * 64 + 32 + quad * 8];
    const int jg = j0 + l15;

    const float SCALE = 0.125f * 1.44269504088896341f;   // /sqrt(64) * log2(e)

    float m = -1e30f, l = 0.f;
    f32x4 o0 = {0.f,0.f,0.f,0.f}, o1 = o0, o2 = o0, o3 = o0;

    const int ntiles = j0 / 64 + 1;
    for (int it64 = 0; it64 < ntiles; ++it64) {
        const int i0 = it64 * 64;

        // ---- scores: S[i][j] = K.Q^T, frags direct from global ----
        float sv[16];
        #pragma unroll
        for (int it = 0; it < 4; ++it) {
            f32x4 s = {0.f, 0.f, 0.f, 0.f};
            short8 a0 = *(const short8*)&Kb[(bhT + i0 + it*16 + l15) * 64 + quad * 8];
            s = __builtin_amdgcn_mfma_f32_16x16x32_bf16(a0, qf0, s, 0, 0, 0);
            short8 a1 = *(const short8*)&Kb[(bhT + i0 + it*16 + l15) * 64 + 32 + quad * 8];
            s = __builtin_amdgcn_mfma_f32_16x16x32_bf16(a1, qf1, s, 0, 0, 0);
            float4 pd4 = *(const float4*)&padf[b * T_SZ + i0 + it*16 + quad*4];
            float pdv[4] = {pd4.x, pd4.y, pd4.z, pd4.w};
            #pragma unroll
            for (int r = 0; r < 4; ++r) {
                int iloc = it * 16 + quad * 4 + r;
                float v = s[r] + pdv[r];
                if (i0 + iloc > jg) v -= 1000.f;     // causal, pre-scale
                sv[it * 4 + r] = v * SCALE;          // exp2 domain
            }
        }

        // ---- online softmax (per j = l15; combine 4 quads via shfl) ----
        float mt = sv[0];
        #pragma unroll
        for (int k = 1; k < 16; ++k) mt = fmaxf(mt, sv[k]);
        mt = fmaxf(mt, __shfl_xor(mt, 16));
        mt = fmaxf(mt, __shfl_xor(mt, 32));
        const float mnew  = fmaxf(m, mt);
        const float alpha = exp2f(m - mnew);
        float p[16], ls = 0.f;
        #pragma unroll
        for (int k = 0; k < 16; ++k) { p[k] = exp2f(sv[k] - mnew); ls += p[k]; }
        ls += __shfl_xor(ls, 16);
        ls += __shfl_xor(ls, 32);
        l = l * alpha + ls;
        m = mnew;
        o0 *= alpha; o1 *= alpha; o2 *= alpha; o3 *= alpha;

        // ---- P^T into wave-private LDS (b64 writes, 2-way = free) ----
        #pragma unroll
        for (int it = 0; it < 4; ++it) {
            short4v pk = {(short)f2bf(p[it*4+0]), (short)f2bf(p[it*4+1]),
                          (short)f2bf(p[it*4+2]), (short)f2bf(p[it*4+3])};
            *(short4v*)&PstT[l15 * 72 + it * 16 + quad * 4] = pk;
        }
        const short8 pf0 = *(const short8*)&PstT[l15 * 72 + quad * 8];
        const short8 pf1 = *(const short8*)&PstT[l15 * 72 + 32 + quad * 8];

        // ---- PV: O^T[d][j] += V^T x P, V^T frags direct from global ----
        short8 a;
        a = *(const short8*)&Vt[((size_t)bh*64 +  0 + l15) * 1024 + i0 + quad*8];
        o0 = __builtin_amdgcn_mfma_f32_16x16x32_bf16(a, pf0, o0, 0, 0, 0);
        a = *(const short8*)&Vt[((size_t)bh*64 +  0 + l15) * 1024 + i0 + 32 + quad*8];
        o0 = __builtin_amdgcn_mfma_f32_16x16x32_bf16(a, pf1, o0, 0, 0, 0);
        a = *(const short8*)&Vt[((size_t)bh*64 + 16 + l15) * 1024 + i0 + quad*8];
        o1 = __builtin_amdgcn_mfma_f32_16x16x32_bf16(a, pf0, o1, 0, 0, 0);
        a = *(const short8*)&Vt[((size_t)bh*64 + 16 + l15) * 1024 + i0 + 32 + quad*8];
        o1 = __builtin_amdgcn_mfma_f32_16x16x32_bf16(a, pf1, o1, 0, 0, 0);
        a = *(const short8*)&Vt[((size_t)bh*64 + 32 + l15) * 1024 + i0 + quad*8];
        o2 = __builtin_amdgcn_mfma_f32_16x16x32_bf16(a, pf0, o2, 0, 0, 0);
        a = *(const short8*)&Vt[((size_t)bh*64 + 32 + l15) * 1024 + i0 + 32 + quad*8];
        o2 = __builtin_amdgcn_mfma_f32_16x16x32_bf16(a, pf1, o2, 0, 0, 0);
        a = *(const short8*)&Vt[((size_t)bh*64 + 48 + l15) * 1024 + i0 + quad*8];
        o3 = __builtin_amdgcn_mfma_f32_16x16x32_bf16(a, pf0, o3, 0, 0, 0);
        a = *(const short8*)&Vt[((size_t)bh*64 + 48 + l15) * 1024 + i0 + 32 + quad*8];
        o3 = __builtin_amdgcn_mfma_f32_16x16x32_bf16(a, pf1, o3, 0, 0, 0);
    }

    // epilogue: lane j = jg (l15), d = dt*16 + quad*4 + r -> float4 stores
    const float inv = 1.f / l;
    float* op = out + ((size_t)b * T_SZ + jg) * (N_H * D_H) + h * D_H + quad * 4;
    *(float4*)(op +  0) = (float4){o0[0]*inv, o0[1]*inv, o0[2]*inv, o0[3]*inv};
    *(float4*)(op + 16) = (float4){o1[0]*inv, o1[1]*inv, o1[2]*inv, o1[3]*inv};
    *(float4*)(op + 32) = (float4){o2[0]*inv, o2[1]*inv, o2[2]*inv, o2[3]*inv};
    *(float4*)(op + 48) = (float4){o3[0]*inv, o3[1]*inv, o3[2]*inv, o3[3]*inv};
}

// ---------------------------------------------------------------------------
extern "C" void kernel_launch(void* const* d_in, const int* in_sizes, int n_in,
                              void* d_out, int out_size, void* d_ws, size_t ws_size,
                              hipStream_t stream) {
    const float* keys    = (const float*)d_in[0];
    const float* queries = (const float*)d_in[1];
    const float* values  = (const float*)d_in[2];
    const float* Wk      = (const float*)d_in[3];
    const float* Wq      = (const float*)d_in[4];
    const float* Wv      = (const float*)d_in[5];
    const int*   key_seq = (const int*)d_in[6];

    const size_t per = (size_t)B_SZ * N_H * T_SZ * D_H;   // 4,194,304 elems
    unsigned short* Kb = (unsigned short*)d_ws;
    unsigned short* Qb = Kb + per;
    unsigned short* Vb = Kb + 2 * per;
    unsigned short* Vt = Kb + 3 * per;
    unsigned short* Wt = Kb + 4 * per;                    // 786432 elems
    float*          padf = (float*)(Wt + 3 * 512 * 512);  // 16B-aligned

    prep_kernel<<<dim3(1024, 3), 256, 0, stream>>>(Wk, Wq, Wv, key_seq, Wt, padf);
    proj_kernel<<<dim3((B_SZ * T_SZ) / 128, 12), 256, 0, stream>>>(
        keys, queries, values, Wt, Kb);
    vt_kernel<<<dim3(16, 64), 256, 0, stream>>>(Vb, Vt);
    attn_kernel<<<dim3(64 * 64), 64, 0, stream>>>(Qb, Kb, Vt, padf, (float*)d_out);
}